// Round 6
// baseline (467.255 us; speedup 1.0000x reference)
//
#include <hip/hip_runtime.h>
#include <hip/hip_cooperative_groups.h>

namespace cg = cooperative_groups;

#define NPTS 8192
#define DIM  128
#define NCLS 64
#define NT   64
#define NTILES (NT * (NT + 1) / 2)   // 2080 triangular tiles
#define FEPS 1e-16f

// ws layout (float elements)
#define WS_S     0
#define WS_SQ    8192
#define WS_CNT   16384
#define WS_OFFS  16448
#define WS_POFF  16520
#define WS_CUR   16592
#define WS_MEM   16656
#define WS_RANK  24848
#define WS_LOSS  33040
#define WS_G     33044      // 16B aligned: 2MB bf16 swizzled features
#define WS_DP    557332     // ~1.1M floats: per-pair distances

typedef float f32x4 __attribute__((ext_vector_type(4)));
typedef short bf16x8 __attribute__((ext_vector_type(8)));

__device__ inline unsigned short f2bf(float x) {
    unsigned u = __float_as_uint(x);
    u += 0x7fffu + ((u >> 16) & 1u);   // RNE
    return (unsigned short)(u >> 16);
}

// ======================= fused cooperative kernel =======================
__launch_bounds__(256, 3)
__global__ void lifted_kernel(const float* __restrict__ feat,
                              const int* __restrict__ labels,
                              float* __restrict__ S,
                              float* __restrict__ sq,
                              int* __restrict__ cnt,
                              int* __restrict__ cur,
                              int* __restrict__ mem,
                              int* __restrict__ rank,
                              float* __restrict__ loss_sum,
                              unsigned short* __restrict__ G16,
                              float* __restrict__ dpair,
                              float* __restrict__ out) {
    cg::grid_group grid = cg::this_grid();

    __shared__ float sqd[512];                 // P2: sqi/sqj (256) ; P3: S gather
    __shared__ int lli[128], llj[128], rki[128], rkj[128];
    __shared__ int s_cnt[NCLS], s_offs[NCLS + 1], s_poff[NCLS + 1];
    __shared__ float redf[4];

    const int tid = threadIdx.x;
    const int w = tid >> 6, lane = tid & 63;
    const int G = gridDim.x;

    // ---------------- P0: prep (bf16 swizzle, norms, counts) ----------------
    {
        const int kl = lane & 31;          // float4 column
        const int rloc = lane >> 5;
        for (int g = blockIdx.x; g < NPTS / 8; g += G) {
            int i = g * 8 + w * 2 + rloc;
            float4 v = ((const float4*)(feat + (size_t)i * DIM))[kl];
            unsigned p0 = ((unsigned)f2bf(v.y) << 16) | (unsigned)f2bf(v.x);
            unsigned p1 = ((unsigned)f2bf(v.w) << 16) | (unsigned)f2bf(v.z);
            int t = i >> 7, m = i & 127;
            int c = kl >> 1, sub = (kl & 1) * 4;
            uint2 val; val.x = p0; val.y = p1;
            *(uint2*)&G16[(size_t)t * 16384 + c * 1024 + m * 8 + sub] = val;
            float s = v.x * v.x + v.y * v.y + v.z * v.z + v.w * v.w;
#pragma unroll
            for (int msk = 1; msk <= 16; msk <<= 1) s += __shfl_xor(s, msk, 64);
            if (kl == 0) {
                sq[i] = s;
                atomicAdd(&cnt[labels[i]], 1);
            }
        }
    }
    __threadfence();
    grid.sync();
    __threadfence();

    // ---------------- P1: per-block offset scan (LDS) + scatter -------------
    if (w == 0) {
        int v = cnt[lane], v2 = v * v;
        int s1 = v, s2 = v2;
#pragma unroll
        for (int o = 1; o < 64; o <<= 1) {
            int t1 = __shfl_up(s1, o, 64);
            int t2 = __shfl_up(s2, o, 64);
            if (lane >= o) { s1 += t1; s2 += t2; }
        }
        s_cnt[lane] = v;
        s_offs[lane] = s1 - v; s_poff[lane] = s2 - v2;
        if (lane == 63) { s_offs[64] = s1; s_poff[64] = s2; }
    }
    __syncthreads();
    {
        int idx = blockIdx.x * 256 + tid;
        if (idx < NPTS) {
            int c = labels[idx];
            int pos = atomicAdd(&cur[c], 1);
            mem[s_offs[c] + pos] = idx;
            rank[idx] = pos;
        }
    }
    __threadfence();
    grid.sync();
    __threadfence();

    // ---------------- P2: persistent triangular gemm_S ----------------------
    {
        const int wr = w >> 1, wc = w & 1;
        const int q = lane >> 4, ml = lane & 15;
        float* sqi = sqd; float* sqj = sqd + 128;
        const uint4* Gp = (const uint4*)G16;

        for (int p = blockIdx.x; p < NTILES; p += G) {
            float disc = 64.5f * 64.5f - 2.0f * (float)p;
            int bt = (int)(64.5f - sqrtf(disc));
            if (bt < 0) bt = 0; if (bt > 63) bt = 63;
            while (bt > 0 && (bt * NT - (bt * (bt - 1)) / 2) > p) --bt;
            while (((bt + 1) * NT - ((bt + 1) * bt) / 2) <= p) ++bt;
            int jt = bt + (p - (bt * NT - (bt * (bt - 1)) / 2));

            const int ib = bt * 128, jb = jt * 128;
            const bool diag = (bt == jt);

            __syncthreads();
            if (tid < 128) {
                int i = ib + tid;
                sqi[tid] = sq[i]; lli[tid] = labels[i]; rki[tid] = rank[i];
            } else {
                int j = jb + tid - 128;
                sqj[tid - 128] = sq[j]; llj[tid - 128] = labels[j]; rkj[tid - 128] = rank[j];
            }
            __syncthreads();

            const bf16x8* A8 = (const bf16x8*)(Gp + (size_t)bt * 2048);
            const bf16x8* B8 = (const bf16x8*)(Gp + (size_t)jt * 2048);

            f32x4 acc[4][4];
#pragma unroll
            for (int a = 0; a < 4; ++a)
#pragma unroll
                for (int b = 0; b < 4; ++b) acc[a][b] = (f32x4){0.f, 0.f, 0.f, 0.f};

#pragma unroll
            for (int s = 0; s < 4; ++s) {
                bf16x8 af[4], bf[4];
                int kbase = (s * 4 + q) * 128;
#pragma unroll
                for (int ii = 0; ii < 4; ++ii) af[ii] = A8[kbase + wr * 64 + ii * 16 + ml];
#pragma unroll
                for (int jj = 0; jj < 4; ++jj) bf[jj] = B8[kbase + wc * 64 + jj * 16 + ml];
#pragma unroll
                for (int ii = 0; ii < 4; ++ii)
#pragma unroll
                    for (int jj = 0; jj < 4; ++jj)
                        acc[ii][jj] = __builtin_amdgcn_mfma_f32_16x16x32_bf16(af[ii], bf[jj], acc[ii][jj], 0, 0, 0);
            }

            int cl[4], lcj[4], rbj[4]; float sj[4];
#pragma unroll
            for (int jj = 0; jj < 4; ++jj) {
                cl[jj] = wc * 64 + jj * 16 + ml;
                lcj[jj] = llj[cl[jj]]; sj[jj] = sqj[cl[jj]]; rbj[jj] = rkj[cl[jj]];
            }
            float colsum[4] = {0.f, 0.f, 0.f, 0.f};

#pragma unroll
            for (int ii = 0; ii < 4; ++ii) {
                int rl = wr * 64 + ii * 16 + q * 4;
                int lri[4], rai[4]; float si4[4];
#pragma unroll
                for (int r = 0; r < 4; ++r) {
                    lri[r] = lli[rl + r]; si4[r] = sqi[rl + r]; rai[r] = rki[rl + r];
                }
                float rs[4] = {0.f, 0.f, 0.f, 0.f};
#pragma unroll
                for (int jj = 0; jj < 4; ++jj)
#pragma unroll
                    for (int r = 0; r < 4; ++r) {
                        float d2 = fmaf(-2.0f, acc[ii][jj][r], si4[r] + sj[jj]);
                        float d = sqrtf(fmaxf(d2, FEPS));
                        float e = __expf(1.0f - d);
                        bool same = (lri[r] == lcj[jj]);
                        float ep = same ? 0.0f : e;
                        rs[r] += ep;
                        colsum[jj] += ep;
                        if (same) {
                            int i = ib + rl + r, j = jb + cl[jj];
                            if (i != j) {
                                int c = lri[r];
                                int n = s_cnt[c], base = s_poff[c];
                                dpair[base + rai[r] * n + rbj[jj]] = d;
                                if (!diag) dpair[base + rbj[jj] * n + rai[r]] = d;
                            }
                        }
                    }
#pragma unroll
                for (int m = 1; m < 16; m <<= 1)
#pragma unroll
                    for (int r = 0; r < 4; ++r) rs[r] += __shfl_xor(rs[r], m, 64);
                if (ml == 0) {
#pragma unroll
                    for (int r = 0; r < 4; ++r) atomicAdd(&S[ib + rl + r], rs[r]);
                }
            }
            if (!diag) {
#pragma unroll
                for (int m = 16; m < 64; m <<= 1)
#pragma unroll
                    for (int jj = 0; jj < 4; ++jj) colsum[jj] += __shfl_xor(colsum[jj], m, 64);
                if (q == 0) {
#pragma unroll
                    for (int jj = 0; jj < 4; ++jj)
                        atomicAdd(&S[jb + cl[jj]], colsum[jj]);
                }
            }
        }
    }
    __threadfence();
    grid.sync();
    __threadfence();

    // ---------------- P3: per-class loss (coalesced dpair reads) ------------
    {
        float total = 0.f;
        for (int wk = blockIdx.x; wk < NCLS * 16; wk += G) {
            int c = wk >> 4, chunk = wk & 15;
            int n = s_cnt[c], base = s_offs[c], pb = s_poff[c];
            __syncthreads();
            for (int m_ = tid; m_ < n && m_ < 512; m_ += 256) sqd[m_] = S[mem[base + m_]];
            __syncthreads();
            for (int a = chunk + 16 * w; a < n; a += 64) {
                float Sa = sqd[a];
                for (int b = lane; b < n; b += 64) {
                    float d = (a == b) ? 1e-8f : dpair[pb + a * n + b];
                    float J = __logf(Sa + sqd[b]) + d;
                    float h = fmaxf(J, 0.0f);
                    total += h * h;
                }
            }
        }
#pragma unroll
        for (int off = 32; off > 0; off >>= 1) total += __shfl_down(total, off, 64);
        __syncthreads();
        if (lane == 0) redf[w] = total;
        __syncthreads();
        if (tid == 0) atomicAdd(loss_sum, redf[0] + redf[1] + redf[2] + redf[3]);
    }
    __threadfence();
    grid.sync();
    __threadfence();

    if (blockIdx.x == 0 && tid == 0) {
        float tot = atomicAdd(loss_sum, 0.0f);
        out[0] = tot / (2.0f * (float)s_poff[64]);
    }
}

// ======================= fallback pipeline (R4, proven) =======================
__global__ void prep_kernel(const float* __restrict__ feat,
                            const int* __restrict__ labels,
                            float* __restrict__ sq,
                            unsigned short* __restrict__ G,
                            int* __restrict__ cnt) {
    int w = threadIdx.x >> 6, lane = threadIdx.x & 63;
    int i = blockIdx.x * 4 + w;
    const float2* row = (const float2*)(feat + (size_t)i * DIM);
    float2 v = row[lane];
    unsigned pack = ((unsigned)f2bf(v.y) << 16) | (unsigned)f2bf(v.x);
    int t = i >> 7, m = i & 127;
    int c = lane >> 2;
    int pos = (lane & 3) * 2;
    *(unsigned*)(&G[(size_t)t * 16384 + c * 1024 + m * 8 + pos]) = pack;
    float s = v.x * v.x + v.y * v.y;
#pragma unroll
    for (int off = 32; off > 0; off >>= 1) s += __shfl_down(s, off, 64);
    if (lane == 0) { sq[i] = s; atomicAdd(&cnt[labels[i]], 1); }
}

__global__ void offsets_kernel(const int* __restrict__ cnt,
                               int* __restrict__ offs, int* __restrict__ poff) {
    int c = threadIdx.x;
    int v = cnt[c], v2 = v * v;
    int s1 = v, s2 = v2;
#pragma unroll
    for (int o = 1; o < 64; o <<= 1) {
        int t1 = __shfl_up(s1, o, 64);
        int t2 = __shfl_up(s2, o, 64);
        if (c >= o) { s1 += t1; s2 += t2; }
    }
    offs[c] = s1 - v; poff[c] = s2 - v2;
    if (c == 63) { offs[64] = s1; poff[64] = s2; }
}

__global__ void scatter_kernel(const int* __restrict__ labels,
                               const int* __restrict__ offs,
                               int* __restrict__ cur, int* __restrict__ mem,
                               int* __restrict__ rank) {
    int n = blockIdx.x * 256 + threadIdx.x;
    int c = labels[n];
    int pos = atomicAdd(&cur[c], 1);
    mem[offs[c] + pos] = n;
    rank[n] = pos;
}

__launch_bounds__(256, 3)
__global__ void gemm_S(const uint4* __restrict__ G,
                       const float* __restrict__ sq,
                       const int* __restrict__ labels,
                       const int* __restrict__ rank,
                       const int* __restrict__ cnt,
                       const int* __restrict__ poff,
                       float* __restrict__ S,
                       float* __restrict__ dpair) {
    int p = blockIdx.x;
    float disc = 64.5f * 64.5f - 2.0f * (float)p;
    int bt = (int)(64.5f - sqrtf(disc));
    if (bt < 0) bt = 0; if (bt > 63) bt = 63;
    while (bt > 0 && (bt * NT - (bt * (bt - 1)) / 2) > p) --bt;
    while (((bt + 1) * NT - ((bt + 1) * bt) / 2) <= p) ++bt;
    int jt = bt + (p - (bt * NT - (bt * (bt - 1)) / 2));

    __shared__ float sqi[128], sqj[128];
    __shared__ int lli[128], llj[128], rki[128], rkj[128];
    __shared__ int s_cnt[NCLS], s_poff[NCLS];

    const int tid = threadIdx.x;
    const int w = tid >> 6, lane = tid & 63;
    const int wr = w >> 1, wc = w & 1;
    const int q = lane >> 4, ml = lane & 15;
    const int ib = bt * 128, jb = jt * 128;
    const bool diag = (bt == jt);

    if (tid < 128) {
        int i = ib + tid;
        sqi[tid] = sq[i]; lli[tid] = labels[i]; rki[tid] = rank[i];
    } else {
        int j = jb + tid - 128;
        sqj[tid - 128] = sq[j]; llj[tid - 128] = labels[j]; rkj[tid - 128] = rank[j];
    }
    if (tid < NCLS) { s_cnt[tid] = cnt[tid]; s_poff[tid] = poff[tid]; }
    __syncthreads();

    const bf16x8* A8 = (const bf16x8*)(G + (size_t)bt * 2048);
    const bf16x8* B8 = (const bf16x8*)(G + (size_t)jt * 2048);

    f32x4 acc[4][4];
#pragma unroll
    for (int a = 0; a < 4; ++a)
#pragma unroll
        for (int b = 0; b < 4; ++b) acc[a][b] = (f32x4){0.f, 0.f, 0.f, 0.f};

#pragma unroll
    for (int s = 0; s < 4; ++s) {
        bf16x8 af[4], bf[4];
        int kbase = (s * 4 + q) * 128;
#pragma unroll
        for (int ii = 0; ii < 4; ++ii) af[ii] = A8[kbase + wr * 64 + ii * 16 + ml];
#pragma unroll
        for (int jj = 0; jj < 4; ++jj) bf[jj] = B8[kbase + wc * 64 + jj * 16 + ml];
#pragma unroll
        for (int ii = 0; ii < 4; ++ii)
#pragma unroll
            for (int jj = 0; jj < 4; ++jj)
                acc[ii][jj] = __builtin_amdgcn_mfma_f32_16x16x32_bf16(af[ii], bf[jj], acc[ii][jj], 0, 0, 0);
    }

    int cl[4], lcj[4], rbj[4]; float sj[4];
#pragma unroll
    for (int jj = 0; jj < 4; ++jj) {
        cl[jj] = wc * 64 + jj * 16 + ml;
        lcj[jj] = llj[cl[jj]]; sj[jj] = sqj[cl[jj]]; rbj[jj] = rkj[cl[jj]];
    }
    float colsum[4] = {0.f, 0.f, 0.f, 0.f};

#pragma unroll
    for (int ii = 0; ii < 4; ++ii) {
        int rl = wr * 64 + ii * 16 + q * 4;
        int lri[4], rai[4]; float si4[4];
#pragma unroll
        for (int r = 0; r < 4; ++r) {
            lri[r] = lli[rl + r]; si4[r] = sqi[rl + r]; rai[r] = rki[rl + r];
        }
        float rs[4] = {0.f, 0.f, 0.f, 0.f};
#pragma unroll
        for (int jj = 0; jj < 4; ++jj)
#pragma unroll
            for (int r = 0; r < 4; ++r) {
                float d2 = fmaf(-2.0f, acc[ii][jj][r], si4[r] + sj[jj]);
                float d = sqrtf(fmaxf(d2, FEPS));
                float e = __expf(1.0f - d);
                bool same = (lri[r] == lcj[jj]);
                float ep = same ? 0.0f : e;
                rs[r] += ep;
                colsum[jj] += ep;
                if (same) {
                    int i = ib + rl + r, j = jb + cl[jj];
                    if (i != j) {
                        int c = lri[r];
                        int n = s_cnt[c], base = s_poff[c];
                        dpair[base + rai[r] * n + rbj[jj]] = d;
                        if (!diag) dpair[base + rbj[jj] * n + rai[r]] = d;
                    }
                }
            }
#pragma unroll
        for (int m = 1; m < 16; m <<= 1)
#pragma unroll
            for (int r = 0; r < 4; ++r) rs[r] += __shfl_xor(rs[r], m, 64);
        if (ml == 0) {
#pragma unroll
            for (int r = 0; r < 4; ++r) atomicAdd(&S[ib + rl + r], rs[r]);
        }
    }
    if (!diag) {
#pragma unroll
        for (int m = 16; m < 64; m <<= 1)
#pragma unroll
            for (int jj = 0; jj < 4; ++jj) colsum[jj] += __shfl_xor(colsum[jj], m, 64);
        if (q == 0) {
#pragma unroll
            for (int jj = 0; jj < 4; ++jj)
                atomicAdd(&S[jb + cl[jj]], colsum[jj]);
        }
    }
}

__global__ void pairB_kernel(const float* __restrict__ S,
                             const int* __restrict__ cnt, const int* __restrict__ offs,
                             const int* __restrict__ poff, const int* __restrict__ mem,
                             const float* __restrict__ dpair,
                             float* __restrict__ loss_sum) {
    __shared__ float redf[4];
    int total = poff[NCLS];
    int stride = gridDim.x * blockDim.x;
    float lsum = 0.f;
    for (int p = blockIdx.x * blockDim.x + threadIdx.x; p < total; p += stride) {
        int lo = 0, hi = NCLS - 1;
        while (lo < hi) {
            int mid = (lo + hi + 1) >> 1;
            if (p >= poff[mid]) lo = mid; else hi = mid - 1;
        }
        int c = lo;
        unsigned pl = (unsigned)(p - poff[c]);
        unsigned n = (unsigned)cnt[c];
        int a = (int)(pl / n);
        int b = (int)(pl - (unsigned)a * n);
        int ia = mem[offs[c] + a], jb_ = mem[offs[c] + b];
        float d = (a == b) ? 1e-8f : dpair[p];
        float J = __logf(S[ia] + S[jb_]) + d;
        float h = fmaxf(J, 0.0f);
        lsum += h * h;
    }
#pragma unroll
    for (int off = 32; off > 0; off >>= 1) lsum += __shfl_down(lsum, off, 64);
    int w = threadIdx.x >> 6;
    if ((threadIdx.x & 63) == 0) redf[w] = lsum;
    __syncthreads();
    if (threadIdx.x == 0) atomicAdd(loss_sum, redf[0] + redf[1] + redf[2] + redf[3]);
}

__global__ void finalize_kernel(const float* __restrict__ loss_sum,
                                const int* __restrict__ poff,
                                float* __restrict__ out) {
    out[0] = loss_sum[0] / (2.0f * (float)poff[NCLS]);
}

extern "C" void kernel_launch(void* const* d_in, const int* in_sizes, int n_in,
                              void* d_out, int out_size, void* d_ws, size_t ws_size,
                              hipStream_t stream) {
    const float* feat = (const float*)d_in[0];
    const int* labels = (const int*)d_in[1];

    float* ws = (float*)d_ws;
    float* S = ws + WS_S;
    float* sq = ws + WS_SQ;
    int* cnt = (int*)(ws + WS_CNT);
    int* offs = (int*)(ws + WS_OFFS);
    int* poff = (int*)(ws + WS_POFF);
    int* cur = (int*)(ws + WS_CUR);
    int* mem = (int*)(ws + WS_MEM);
    int* rank = (int*)(ws + WS_RANK);
    float* loss_sum = ws + WS_LOSS;
    unsigned short* G16 = (unsigned short*)(ws + WS_G);
    const uint4* G4 = (const uint4*)(ws + WS_G);
    float* dpair = ws + WS_DP;
    float* outp = (float*)d_out;

    hipMemsetAsync(d_ws, 0, (WS_LOSS + 1) * sizeof(float), stream);

    // cooperative path: size grid from actual occupancy (capture-safe query)
    int bpc = 0;
    hipError_t qe = hipOccupancyMaxActiveBlocksPerMultiprocessor(&bpc, lifted_kernel, 256, 0);
    int grid = (qe == hipSuccess) ? bpc * 256 : 0;
    if (grid > 768) grid = 768;

    bool done = false;
    if (grid >= 256) {
        void* args[] = {(void*)&feat, (void*)&labels, (void*)&S, (void*)&sq,
                        (void*)&cnt, (void*)&cur, (void*)&mem, (void*)&rank,
                        (void*)&loss_sum, (void*)&G16, (void*)&dpair, (void*)&outp};
        hipError_t le = hipLaunchCooperativeKernel((void*)lifted_kernel,
                                                   dim3(grid), dim3(256), args, 0, stream);
        done = (le == hipSuccess);
    }

    if (!done) {
        prep_kernel<<<NPTS / 4, 256, 0, stream>>>(feat, labels, sq, G16, cnt);
        offsets_kernel<<<1, 64, 0, stream>>>(cnt, offs, poff);
        scatter_kernel<<<NPTS / 256, 256, 0, stream>>>(labels, offs, cur, mem, rank);
        gemm_S<<<NTILES, 256, 0, stream>>>(G4, sq, labels, rank, cnt, poff, S, dpair);
        pairB_kernel<<<512, 256, 0, stream>>>(S, cnt, offs, poff, mem, dpair, loss_sum);
        finalize_kernel<<<1, 1, 0, stream>>>(loss_sum, poff, outp);
    }
}

// Round 7
// 195.237 us; speedup vs baseline: 2.3933x; 2.3933x over previous
//
#include <hip/hip_runtime.h>

#define NPTS 8192
#define DIM  128
#define NCLS 64
#define NT   64
#define NTILES (NT * (NT + 1) / 2)   // 2080 triangular tiles
#define FEPS 1e-16f

// ws layout (float elements). [0, WS_ZEND) is memset to 0 each launch.
#define WS_S     0          // 8192: S_i
#define WS_CNT   8192       // 64 ints
#define WS_LOSS  8256       // 1 float
#define WS_DONE  8257       // 1 uint (completion counter)
#define WS_ZEND  8258
#define WS_SQ    8258       // 8192 floats
#define WS_OFFS  16450      // 65 ints
#define WS_POFF  16515      // 65 ints
#define WS_MEM   16580      // 8192 ints
#define WS_RANK  24772      // 8192 ints
#define WS_G     32964      // 32964*4 = 131856, 131856/16 = 8241 -> 16B aligned; 2MB bf16
#define WS_DP    557252     // ~1.1M floats: per-pair canonical distances

typedef float f32x4 __attribute__((ext_vector_type(4)));
typedef short bf16x8 __attribute__((ext_vector_type(8)));

__device__ inline unsigned short f2bf(float x) {
    unsigned u = __float_as_uint(x);
    u += 0x7fffu + ((u >> 16) & 1u);   // RNE
    return (unsigned short)(u >> 16);
}

// ---- prep: bf16 swizzle + squared norms + class counts (1024 blocks) ----
// G layout (u16 units): tile t=i>>7 (16384 each) | chunk c=k>>3 (1024 each)
//                       | m=i&127 (8 each) | k&7
__global__ void prep_kernel(const float* __restrict__ feat,
                            const int* __restrict__ labels,
                            float* __restrict__ sq,
                            unsigned short* __restrict__ G,
                            int* __restrict__ cnt) {
    const int tid = threadIdx.x;
    const int w = tid >> 6, lane = tid & 63;
    const int kl = lane & 31;          // float4 column
    const int rloc = lane >> 5;        // row within wave pair
    int i = blockIdx.x * 8 + w * 2 + rloc;
    float4 v = ((const float4*)(feat + (size_t)i * DIM))[kl];
    unsigned p0 = ((unsigned)f2bf(v.y) << 16) | (unsigned)f2bf(v.x);
    unsigned p1 = ((unsigned)f2bf(v.w) << 16) | (unsigned)f2bf(v.z);
    int t = i >> 7, m = i & 127;
    int c = kl >> 1, sub = (kl & 1) * 4;
    uint2 val; val.x = p0; val.y = p1;
    *(uint2*)&G[(size_t)t * 16384 + c * 1024 + m * 8 + sub] = val;
    float s = v.x * v.x + v.y * v.y + v.z * v.z + v.w * v.w;
#pragma unroll
    for (int msk = 1; msk <= 16; msk <<= 1) s += __shfl_xor(s, msk, 64);
    if (kl == 0) {
        sq[i] = s;
        atomicAdd(&cnt[labels[i]], 1);
    }
}

// ---- offsets scan + scatter, single block ----
__global__ void offscatter_kernel(const int* __restrict__ labels,
                                  const int* __restrict__ cnt,
                                  int* __restrict__ offs, int* __restrict__ poff,
                                  int* __restrict__ mem, int* __restrict__ rank) {
    __shared__ int s_offs[NCLS];
    __shared__ int s_cur[NCLS];
    const int tid = threadIdx.x;
    if (tid < NCLS) s_cur[tid] = 0;
    if (tid < 64 && (threadIdx.x >> 6) == 0) {
        int v = cnt[tid], v2 = v * v;
        int s1 = v, s2 = v2;
#pragma unroll
        for (int o = 1; o < 64; o <<= 1) {
            int t1 = __shfl_up(s1, o, 64);
            int t2 = __shfl_up(s2, o, 64);
            if (tid >= o) { s1 += t1; s2 += t2; }
        }
        s_offs[tid] = s1 - v;
        offs[tid] = s1 - v; poff[tid] = s2 - v2;
        if (tid == 63) { offs[64] = s1; poff[64] = s2; }
    }
    __syncthreads();
    for (int idx = tid; idx < NPTS; idx += 256) {
        int c = labels[idx];
        int pos = atomicAdd(&s_cur[c], 1);
        mem[s_offs[c] + pos] = idx;
        rank[idx] = pos;
    }
}

// ---- main triangular N^2 pass ----
__launch_bounds__(256, 3)
__global__ void gemm_S(const uint4* __restrict__ G,
                       const float* __restrict__ sq,
                       const int* __restrict__ labels,
                       const int* __restrict__ rank,
                       const int* __restrict__ cnt,
                       const int* __restrict__ poff,
                       float* __restrict__ S,
                       float* __restrict__ dpair) {
    int p = blockIdx.x;
    float disc = 64.5f * 64.5f - 2.0f * (float)p;
    int bt = (int)(64.5f - sqrtf(disc));
    if (bt < 0) bt = 0; if (bt > 63) bt = 63;
    while (bt > 0 && (bt * NT - (bt * (bt - 1)) / 2) > p) --bt;
    while (((bt + 1) * NT - ((bt + 1) * bt) / 2) <= p) ++bt;
    int jt = bt + (p - (bt * NT - (bt * (bt - 1)) / 2));

    __shared__ float sqi[128], sqj[128];
    __shared__ int lli[128], llj[128], rki[128], rkj[128];
    __shared__ int s_cnt[NCLS], s_poff[NCLS];

    const int tid = threadIdx.x;
    const int w = tid >> 6, lane = tid & 63;
    const int wr = w >> 1, wc = w & 1;
    const int q = lane >> 4, ml = lane & 15;
    const int ib = bt * 128, jb = jt * 128;
    const bool diag = (bt == jt);

    if (tid < 128) {
        int i = ib + tid;
        sqi[tid] = sq[i]; lli[tid] = labels[i]; rki[tid] = rank[i];
    } else {
        int j = jb + tid - 128;
        sqj[tid - 128] = sq[j]; llj[tid - 128] = labels[j]; rkj[tid - 128] = rank[j];
    }
    if (tid < NCLS) { s_cnt[tid] = cnt[tid]; s_poff[tid] = poff[tid]; }
    __syncthreads();

    const bf16x8* A8 = (const bf16x8*)(G + (size_t)bt * 2048);
    const bf16x8* B8 = (const bf16x8*)(G + (size_t)jt * 2048);

    f32x4 acc[4][4];
#pragma unroll
    for (int a = 0; a < 4; ++a)
#pragma unroll
        for (int b = 0; b < 4; ++b) acc[a][b] = (f32x4){0.f, 0.f, 0.f, 0.f};

#pragma unroll
    for (int s = 0; s < 4; ++s) {
        bf16x8 af[4], bf[4];
        int kbase = (s * 4 + q) * 128;
#pragma unroll
        for (int ii = 0; ii < 4; ++ii) af[ii] = A8[kbase + wr * 64 + ii * 16 + ml];
#pragma unroll
        for (int jj = 0; jj < 4; ++jj) bf[jj] = B8[kbase + wc * 64 + jj * 16 + ml];
#pragma unroll
        for (int ii = 0; ii < 4; ++ii)
#pragma unroll
            for (int jj = 0; jj < 4; ++jj)
                acc[ii][jj] = __builtin_amdgcn_mfma_f32_16x16x32_bf16(af[ii], bf[jj], acc[ii][jj], 0, 0, 0);
    }

    int cl[4], lcj[4], rbj[4]; float sj[4];
#pragma unroll
    for (int jj = 0; jj < 4; ++jj) {
        cl[jj] = wc * 64 + jj * 16 + ml;
        lcj[jj] = llj[cl[jj]]; sj[jj] = sqj[cl[jj]]; rbj[jj] = rkj[cl[jj]];
    }
    float colsum[4] = {0.f, 0.f, 0.f, 0.f};

#pragma unroll
    for (int ii = 0; ii < 4; ++ii) {
        int rl = wr * 64 + ii * 16 + q * 4;
        int lri[4], rai[4]; float si4[4];
#pragma unroll
        for (int r = 0; r < 4; ++r) {
            lri[r] = lli[rl + r]; si4[r] = sqi[rl + r]; rai[r] = rki[rl + r];
        }
        float rs[4] = {0.f, 0.f, 0.f, 0.f};
#pragma unroll
        for (int jj = 0; jj < 4; ++jj)
#pragma unroll
            for (int r = 0; r < 4; ++r) {
                float d2 = fmaf(-2.0f, acc[ii][jj][r], si4[r] + sj[jj]);
                float d = sqrtf(fmaxf(d2, FEPS));
                float e = __expf(1.0f - d);
                bool same = (lri[r] == lcj[jj]);
                float ep = same ? 0.0f : e;
                rs[r] += ep;
                colsum[jj] += ep;
                if (same) {
                    int i = ib + rl + r, j = jb + cl[jj];
                    if (i != j) {
                        int c = lri[r];
                        int n = s_cnt[c], base = s_poff[c];
                        int hi = max(rai[r], rbj[jj]), lo = min(rai[r], rbj[jj]);
                        dpair[base + hi * n + lo] = d;   // canonical slot, written once
                    }
                }
            }
#pragma unroll
        for (int m = 1; m < 16; m <<= 1)
#pragma unroll
            for (int r = 0; r < 4; ++r) rs[r] += __shfl_xor(rs[r], m, 64);
        if (ml == 0) {
#pragma unroll
            for (int r = 0; r < 4; ++r) atomicAdd(&S[ib + rl + r], rs[r]);
        }
    }
    if (!diag) {
#pragma unroll
        for (int m = 16; m < 64; m <<= 1)
#pragma unroll
            for (int jj = 0; jj < 4; ++jj) colsum[jj] += __shfl_xor(colsum[jj], m, 64);
        if (q == 0) {
#pragma unroll
            for (int jj = 0; jj < 4; ++jj)
                atomicAdd(&S[jb + cl[jj]], colsum[jj]);
        }
    }
}

// ---- per-class loss + inline finalize (completion counter) ----
__global__ void pairB_kernel(const float* __restrict__ S,
                             const int* __restrict__ cnt, const int* __restrict__ offs,
                             const int* __restrict__ poff, const int* __restrict__ mem,
                             const float* __restrict__ dpair,
                             float* __restrict__ loss_sum,
                             unsigned int* __restrict__ done,
                             float* __restrict__ out) {
    __shared__ float Sg[512];
    __shared__ float redf[4];
    const int tid = threadIdx.x;
    const int w = tid >> 6, lane = tid & 63;
    const int c = blockIdx.x >> 4, chunk = blockIdx.x & 15;
    const int n = cnt[c], base = offs[c], pb = poff[c];

    for (int m_ = tid; m_ < n && m_ < 512; m_ += 256) Sg[m_] = S[mem[base + m_]];
    __syncthreads();

    float total = 0.f;
    for (int a = chunk + 16 * w; a < n; a += 64) {
        float Sa = (a < 512) ? Sg[a] : S[mem[base + a]];
        int an = a * n;
        for (int b = lane; b < n; b += 64) {
            float Sb = (b < 512) ? Sg[b] : S[mem[base + b]];
            float d;
            if (b == a) d = 1e-8f;
            else {
                int idx = (b < a) ? (an + b) : (b * n + a);
                d = dpair[pb + idx];
            }
            float J = __logf(Sa + Sb) + d;
            float h = fmaxf(J, 0.0f);
            total += h * h;
        }
    }
#pragma unroll
    for (int off = 32; off > 0; off >>= 1) total += __shfl_down(total, off, 64);
    if (lane == 0) redf[w] = total;
    __syncthreads();
    if (tid == 0) {
        atomicAdd(loss_sum, redf[0] + redf[1] + redf[2] + redf[3]);
        __threadfence();
        unsigned int t = atomicAdd(done, 1u);
        if (t == gridDim.x - 1) {
            float tot = atomicAdd(loss_sum, 0.0f);   // coherent read-back
            out[0] = tot / (2.0f * (float)poff[NCLS]);
        }
    }
}

extern "C" void kernel_launch(void* const* d_in, const int* in_sizes, int n_in,
                              void* d_out, int out_size, void* d_ws, size_t ws_size,
                              hipStream_t stream) {
    const float* feat = (const float*)d_in[0];
    const int* labels = (const int*)d_in[1];

    float* ws = (float*)d_ws;
    float* S = ws + WS_S;
    int* cnt = (int*)(ws + WS_CNT);
    float* loss_sum = ws + WS_LOSS;
    unsigned int* done = (unsigned int*)(ws + WS_DONE);
    float* sq = ws + WS_SQ;
    int* offs = (int*)(ws + WS_OFFS);
    int* poff = (int*)(ws + WS_POFF);
    int* mem = (int*)(ws + WS_MEM);
    int* rank = (int*)(ws + WS_RANK);
    unsigned short* G16 = (unsigned short*)(ws + WS_G);
    const uint4* G4 = (const uint4*)(ws + WS_G);
    float* dpair = ws + WS_DP;
    float* outp = (float*)d_out;

    hipMemsetAsync(d_ws, 0, WS_ZEND * sizeof(float), stream);                     // node 1
    prep_kernel<<<NPTS / 8, 256, 0, stream>>>(feat, labels, sq, G16, cnt);        // node 2
    offscatter_kernel<<<1, 256, 0, stream>>>(labels, cnt, offs, poff, mem, rank); // node 3
    gemm_S<<<NTILES, 256, 0, stream>>>(G4, sq, labels, rank, cnt, poff, S, dpair);// node 4
    pairB_kernel<<<NCLS * 16, 256, 0, stream>>>(S, cnt, offs, poff, mem, dpair,
                                                loss_sum, done, outp);            // node 5
}

// Round 8
// 141.890 us; speedup vs baseline: 3.2931x; 1.3760x over previous
//
#include <hip/hip_runtime.h>

#define NPTS 8192
#define DIM  128
#define NCLS 64
#define NT   64
#define NTILES (NT * (NT + 1) / 2)   // 2080 triangular tiles
#define FEPS 1e-16f

// ws layout (float elements). [0, WS_ZEND) is memset to 0 each launch.
#define WS_S     0          // 8192: S_i
#define WS_CNT   8192       // 64 ints (written wholesale by offscatter)
#define WS_LOSS  8256       // 1 float
#define WS_DONE  8257       // 1 uint
#define WS_ZEND  8258
#define WS_SQ    8258       // 8192 floats
#define WS_OFFS  16450      // 65 ints
#define WS_POFF  16515      // 65 ints
#define WS_MEM   16580      // 8192 ints
#define WS_RANK  24772      // 8192 ints
#define WS_G     32964      // 16B aligned; 2MB bf16 swizzled features
#define WS_DP    557252     // ~1.1M floats: canonical per-pair distances

typedef float f32x4 __attribute__((ext_vector_type(4)));
typedef short bf16x8 __attribute__((ext_vector_type(8)));

__device__ inline unsigned short f2bf(float x) {
    unsigned u = __float_as_uint(x);
    u += 0x7fffu + ((u >> 16) & 1u);   // RNE
    return (unsigned short)(u >> 16);
}

__device__ inline float fast_sqrt(float x) {
    float r;
    asm("v_sqrt_f32 %0, %1" : "=v"(r) : "v"(x));   // ~1 ULP, 1 inst (vs ~6-inst precise seq)
    return r;
}

// ---- prep: bf16 swizzle + squared norms (NO count atomics) ----
// G layout (u16 units): tile t=i>>7 (16384 each) | chunk c=k>>3 (1024 each)
//                       | m=i&127 (8 each) | k&7
__global__ void prep_kernel(const float* __restrict__ feat,
                            float* __restrict__ sq,
                            unsigned short* __restrict__ G) {
    const int tid = threadIdx.x;
    const int w = tid >> 6, lane = tid & 63;
    const int kl = lane & 31;
    const int rloc = lane >> 5;
    int i = blockIdx.x * 8 + w * 2 + rloc;
    float4 v = ((const float4*)(feat + (size_t)i * DIM))[kl];
    unsigned p0 = ((unsigned)f2bf(v.y) << 16) | (unsigned)f2bf(v.x);
    unsigned p1 = ((unsigned)f2bf(v.w) << 16) | (unsigned)f2bf(v.z);
    int t = i >> 7, m = i & 127;
    int c = kl >> 1, sub = (kl & 1) * 4;
    uint2 val; val.x = p0; val.y = p1;
    *(uint2*)&G[(size_t)t * 16384 + c * 1024 + m * 8 + sub] = val;
    float s = v.x * v.x + v.y * v.y + v.z * v.z + v.w * v.w;
#pragma unroll
    for (int msk = 1; msk <= 16; msk <<= 1) s += __shfl_xor(s, msk, 64);
    if (kl == 0) sq[i] = s;
}

// ---- histogram (LDS) + scan + scatter, single block ----
__global__ void offscatter_kernel(const int* __restrict__ labels,
                                  int* __restrict__ cnt,
                                  int* __restrict__ offs, int* __restrict__ poff,
                                  int* __restrict__ mem, int* __restrict__ rank) {
    __shared__ int hist[NCLS];
    __shared__ int s_offs[NCLS];
    __shared__ int s_cur[NCLS];
    const int tid = threadIdx.x;
    if (tid < NCLS) { hist[tid] = 0; s_cur[tid] = 0; }
    __syncthreads();
    for (int idx = tid; idx < NPTS; idx += 256) atomicAdd(&hist[labels[idx]], 1);
    __syncthreads();
    if (tid < 64) {   // wave 0 scans
        int v = hist[tid], v2 = v * v;
        int s1 = v, s2 = v2;
#pragma unroll
        for (int o = 1; o < 64; o <<= 1) {
            int t1 = __shfl_up(s1, o, 64);
            int t2 = __shfl_up(s2, o, 64);
            if (tid >= o) { s1 += t1; s2 += t2; }
        }
        s_offs[tid] = s1 - v;
        cnt[tid] = v;
        offs[tid] = s1 - v; poff[tid] = s2 - v2;
        if (tid == 63) { offs[64] = s1; poff[64] = s2; }
    }
    __syncthreads();
    for (int idx = tid; idx < NPTS; idx += 256) {
        int c = labels[idx];
        int pos = atomicAdd(&s_cur[c], 1);
        mem[s_offs[c] + pos] = idx;
        rank[idx] = pos;
    }
}

// ---- main triangular N^2 pass ----
__launch_bounds__(256, 3)
__global__ void gemm_S(const uint4* __restrict__ G,
                       const float* __restrict__ sq,
                       const int* __restrict__ labels,
                       const int* __restrict__ rank,
                       const int* __restrict__ cnt,
                       const int* __restrict__ poff,
                       float* __restrict__ S,
                       float* __restrict__ dpair) {
    int p = blockIdx.x;
    float disc = 64.5f * 64.5f - 2.0f * (float)p;
    int bt = (int)(64.5f - fast_sqrt(disc));
    if (bt < 0) bt = 0; if (bt > 63) bt = 63;
    while (bt > 0 && (bt * NT - (bt * (bt - 1)) / 2) > p) --bt;
    while (((bt + 1) * NT - ((bt + 1) * bt) / 2) <= p) ++bt;
    int jt = bt + (p - (bt * NT - (bt * (bt - 1)) / 2));

    __shared__ float sqi[128], sqj[128];
    __shared__ int lli[128], llj[128], rki[128], rkj[128];
    __shared__ int s_cnt[NCLS], s_poff[NCLS];

    const int tid = threadIdx.x;
    const int w = tid >> 6, lane = tid & 63;
    const int wr = w >> 1, wc = w & 1;
    const int q = lane >> 4, ml = lane & 15;
    const int ib = bt * 128, jb = jt * 128;
    const bool diag = (bt == jt);

    if (tid < 128) {
        int i = ib + tid;
        sqi[tid] = sq[i]; lli[tid] = labels[i]; rki[tid] = rank[i];
    } else {
        int j = jb + tid - 128;
        sqj[tid - 128] = sq[j]; llj[tid - 128] = labels[j]; rkj[tid - 128] = rank[j];
    }
    if (tid < NCLS) { s_cnt[tid] = cnt[tid]; s_poff[tid] = poff[tid]; }
    __syncthreads();

    const bf16x8* A8 = (const bf16x8*)(G + (size_t)bt * 2048);
    const bf16x8* B8 = (const bf16x8*)(G + (size_t)jt * 2048);

    f32x4 acc[4][4];
#pragma unroll
    for (int a = 0; a < 4; ++a)
#pragma unroll
        for (int b = 0; b < 4; ++b) acc[a][b] = (f32x4){0.f, 0.f, 0.f, 0.f};

#pragma unroll
    for (int s = 0; s < 4; ++s) {
        bf16x8 af[4], bf[4];
        int kbase = (s * 4 + q) * 128;
#pragma unroll
        for (int ii = 0; ii < 4; ++ii) af[ii] = A8[kbase + wr * 64 + ii * 16 + ml];
#pragma unroll
        for (int jj = 0; jj < 4; ++jj) bf[jj] = B8[kbase + wc * 64 + jj * 16 + ml];
#pragma unroll
        for (int ii = 0; ii < 4; ++ii)
#pragma unroll
            for (int jj = 0; jj < 4; ++jj)
                acc[ii][jj] = __builtin_amdgcn_mfma_f32_16x16x32_bf16(af[ii], bf[jj], acc[ii][jj], 0, 0, 0);
    }

    int cl[4], lcj[4], rbj[4]; float sj[4];
#pragma unroll
    for (int jj = 0; jj < 4; ++jj) {
        cl[jj] = wc * 64 + jj * 16 + ml;
        lcj[jj] = llj[cl[jj]]; sj[jj] = sqj[cl[jj]]; rbj[jj] = rkj[cl[jj]];
    }
    float colsum[4] = {0.f, 0.f, 0.f, 0.f};

#pragma unroll
    for (int ii = 0; ii < 4; ++ii) {
        int rl = wr * 64 + ii * 16 + q * 4;
        int lri[4], rai[4]; float si4[4];
#pragma unroll
        for (int r = 0; r < 4; ++r) {
            lri[r] = lli[rl + r]; si4[r] = sqi[rl + r]; rai[r] = rki[rl + r];
        }
        float rs[4] = {0.f, 0.f, 0.f, 0.f};
#pragma unroll
        for (int jj = 0; jj < 4; ++jj)
#pragma unroll
            for (int r = 0; r < 4; ++r) {
                float d2 = fmaf(-2.0f, acc[ii][jj][r], si4[r] + sj[jj]);
                float d = fast_sqrt(fmaxf(d2, FEPS));
                float e = __expf(1.0f - d);
                bool same = (lri[r] == lcj[jj]);
                float ep = same ? 0.0f : e;
                rs[r] += ep;
                colsum[jj] += ep;
                if (same) {
                    int i = ib + rl + r, j = jb + cl[jj];
                    if (i != j) {
                        int c = lri[r];
                        int n = s_cnt[c], base = s_poff[c];
                        int hi = max(rai[r], rbj[jj]), lo = min(rai[r], rbj[jj]);
                        dpair[base + hi * n + lo] = d;   // canonical slot, written once
                    }
                }
            }
#pragma unroll
        for (int m = 1; m < 16; m <<= 1)
#pragma unroll
            for (int r = 0; r < 4; ++r) rs[r] += __shfl_xor(rs[r], m, 64);
        if (ml == 0) {
#pragma unroll
            for (int r = 0; r < 4; ++r) atomicAdd(&S[ib + rl + r], rs[r]);
        }
    }
    if (!diag) {
#pragma unroll
        for (int m = 16; m < 64; m <<= 1)
#pragma unroll
            for (int jj = 0; jj < 4; ++jj) colsum[jj] += __shfl_xor(colsum[jj], m, 64);
        if (q == 0) {
#pragma unroll
            for (int jj = 0; jj < 4; ++jj)
                atomicAdd(&S[jb + cl[jj]], colsum[jj]);
        }
    }
}

// ---- per-class loss + inline finalize (completion counter) ----
__global__ void pairB_kernel(const float* __restrict__ S,
                             const int* __restrict__ cnt, const int* __restrict__ offs,
                             const int* __restrict__ poff, const int* __restrict__ mem,
                             const float* __restrict__ dpair,
                             float* __restrict__ loss_sum,
                             unsigned int* __restrict__ done,
                             float* __restrict__ out) {
    __shared__ float Sg[512];
    __shared__ float redf[4];
    const int tid = threadIdx.x;
    const int w = tid >> 6, lane = tid & 63;
    const int c = blockIdx.x >> 2, chunk = blockIdx.x & 3;
    const int n = cnt[c], base = offs[c], pb = poff[c];

    for (int m_ = tid; m_ < n && m_ < 512; m_ += 256) Sg[m_] = S[mem[base + m_]];
    __syncthreads();

    float total = 0.f;
    for (int a = chunk + 4 * w; a < n; a += 16) {
        float Sa = (a < 512) ? Sg[a] : S[mem[base + a]];
        int an = a * n;
        for (int b = lane; b < n; b += 64) {
            float Sb = (b < 512) ? Sg[b] : S[mem[base + b]];
            float d;
            if (b == a) d = 1e-8f;
            else {
                int idx = (b < a) ? (an + b) : (b * n + a);
                d = dpair[pb + idx];
            }
            float J = __logf(Sa + Sb) + d;
            float h = fmaxf(J, 0.0f);
            total += h * h;
        }
    }
#pragma unroll
    for (int off = 32; off > 0; off >>= 1) total += __shfl_down(total, off, 64);
    if (lane == 0) redf[w] = total;
    __syncthreads();
    if (tid == 0) {
        atomicAdd(loss_sum, redf[0] + redf[1] + redf[2] + redf[3]);
        __threadfence();
        unsigned int t = atomicAdd(done, 1u);
        if (t == gridDim.x - 1) {
            float tot = atomicAdd(loss_sum, 0.0f);   // coherent read-back
            out[0] = tot / (2.0f * (float)poff[NCLS]);
        }
    }
}

extern "C" void kernel_launch(void* const* d_in, const int* in_sizes, int n_in,
                              void* d_out, int out_size, void* d_ws, size_t ws_size,
                              hipStream_t stream) {
    const float* feat = (const float*)d_in[0];
    const int* labels = (const int*)d_in[1];

    float* ws = (float*)d_ws;
    float* S = ws + WS_S;
    int* cnt = (int*)(ws + WS_CNT);
    float* loss_sum = ws + WS_LOSS;
    unsigned int* done = (unsigned int*)(ws + WS_DONE);
    float* sq = ws + WS_SQ;
    int* offs = (int*)(ws + WS_OFFS);
    int* poff = (int*)(ws + WS_POFF);
    int* mem = (int*)(ws + WS_MEM);
    int* rank = (int*)(ws + WS_RANK);
    unsigned short* G16 = (unsigned short*)(ws + WS_G);
    const uint4* G4 = (const uint4*)(ws + WS_G);
    float* dpair = ws + WS_DP;
    float* outp = (float*)d_out;

    hipMemsetAsync(d_ws, 0, WS_ZEND * sizeof(float), stream);                       // node 1
    prep_kernel<<<NPTS / 8, 256, 0, stream>>>(feat, sq, G16);                       // node 2
    offscatter_kernel<<<1, 256, 0, stream>>>(labels, cnt, offs, poff, mem, rank);   // node 3
    gemm_S<<<NTILES, 256, 0, stream>>>(G4, sq, labels, rank, cnt, poff, S, dpair);  // node 4
    pairB_kernel<<<NCLS * 4, 256, 0, stream>>>(S, cnt, offs, poff, mem, dpair,
                                               loss_sum, done, outp);               // node 5
}